// Round 1
// baseline (2624.632 us; speedup 1.0000x reference)
//
#include <hip/hip_runtime.h>
#include <math.h>

// Problem constants (from reference): H=4 heads, C=32, HID=128, 3 layers, B=2048, D=480
#define NHEAD   4
#define CDIM    32
#define HIDDIM  128
#define NLAYERS 3
#define DIN     480
#define LN_EPS  1e-5f

// ---------------------------------------------------------------------------
// CSR build: in-degree histogram (edges + self loops)
// ---------------------------------------------------------------------------
__global__ void hist_kernel(const int* __restrict__ ei, int* __restrict__ deg, int E, int N) {
    int i = blockIdx.x * 256 + threadIdx.x;
    int tot = E + N;
    if (i >= tot) return;
    int d = (i < E) ? ei[E + i] : (i - E);   // ei[0:E]=src, ei[E:2E]=dst; tail = self loops
    atomicAdd(&deg[d], 1);
}

// Exclusive prefix sum over deg[N] -> rowptr[N+1]; also copies into cursor[N].
// Single block of 1024 threads (N <= 131072 -> 128 elems/thread sequential).
__global__ __launch_bounds__(1024) void scan_kernel(const int* __restrict__ deg,
                                                    int* __restrict__ rowptr,
                                                    int* __restrict__ cursor, int N) {
    __shared__ int part[1024];
    int t = threadIdx.x;
    int chunk = (N + 1023) >> 10;
    int beg = t * chunk;
    int end = min(N, beg + chunk);
    int s = 0;
    for (int i = beg; i < end; ++i) s += deg[i];
    part[t] = s;
    __syncthreads();
    for (int off = 1; off < 1024; off <<= 1) {
        int v = (t >= off) ? part[t - off] : 0;
        __syncthreads();
        part[t] += v;
        __syncthreads();
    }
    int run = (t == 0) ? 0 : part[t - 1];
    for (int i = beg; i < end; ++i) {
        rowptr[i] = run;
        cursor[i] = run;
        run += deg[i];
    }
    if (beg < N && end == N) rowptr[N] = run;
}

__global__ void fill_kernel(const int* __restrict__ ei, int* __restrict__ cursor,
                            int* __restrict__ col, int E, int N) {
    int i = blockIdx.x * 256 + threadIdx.x;
    int tot = E + N;
    if (i >= tot) return;
    int s, d;
    if (i < E) { s = ei[i]; d = ei[E + i]; }
    else       { s = d = i - E; }
    int pos = atomicAdd(&cursor[d], 1);
    col[pos] = s;
}

// ---------------------------------------------------------------------------
// f32 tiled GEMM: C[n,j] = act(sum_k A[n,k]*W[k,j] + bias[j]); 128 output cols.
// Block 256 thr, tile 64 nodes x 128 cols, Kt=16. Requires N%64==0, K%16==0.
// ---------------------------------------------------------------------------
__global__ __launch_bounds__(256) void gemm128_kernel(const float* __restrict__ A,
                                                      const float* __restrict__ W,
                                                      const float* __restrict__ bias,
                                                      float* __restrict__ C,
                                                      int N, int K, int do_relu) {
    __shared__ float As[64 * 17];     // +1 pad: conflict-free a-broadcast reads
    __shared__ float Ws[16 * 128];
    const int tid = threadIdx.x;
    const int bn  = blockIdx.x * 64;
    const int tj  = tid & 15;         // col group: cols tj*4..+3 and 64+tj*4..+3
    const int tn  = tid >> 4;         // node group: nodes tn*4..+3
    const int c0  = tj * 4;
    const int c1  = 64 + tj * 4;

    float acc[4][8];
#pragma unroll
    for (int i = 0; i < 4; ++i)
#pragma unroll
        for (int u = 0; u < 8; ++u) acc[i][u] = 0.f;

    const int la_c  = tid & 15;   // A staging: 16 rows x 16 cols per pass, 4 passes
    const int la_r0 = tid >> 4;

    for (int kt = 0; kt < K; kt += 16) {
#pragma unroll
        for (int p = 0; p < 4; ++p) {
            int r = la_r0 + p * 16;
            As[r * 17 + la_c] = A[(size_t)(bn + r) * K + kt + la_c];
        }
        {   // W tile rows kt..kt+15 are 2048 contiguous floats
            const float4* Wv  = (const float4*)(W + (size_t)kt * 128);
            float4*       Wsv = (float4*)Ws;
            Wsv[tid * 2]     = Wv[tid * 2];
            Wsv[tid * 2 + 1] = Wv[tid * 2 + 1];
        }
        __syncthreads();
#pragma unroll
        for (int kk = 0; kk < 16; ++kk) {
            float av[4];
#pragma unroll
            for (int i = 0; i < 4; ++i) av[i] = As[(tn * 4 + i) * 17 + kk];
            const float* wr = Ws + kk * 128;
            float4 w0 = *(const float4*)(wr + c0);
            float4 w1 = *(const float4*)(wr + c1);
            float wv[8] = {w0.x, w0.y, w0.z, w0.w, w1.x, w1.y, w1.z, w1.w};
#pragma unroll
            for (int i = 0; i < 4; ++i)
#pragma unroll
                for (int u = 0; u < 8; ++u)
                    acc[i][u] = fmaf(av[i], wv[u], acc[i][u]);
        }
        __syncthreads();
    }

    float4 b0 = make_float4(0.f, 0.f, 0.f, 0.f), b1 = b0;
    if (bias) { b0 = *(const float4*)(bias + c0); b1 = *(const float4*)(bias + c1); }
#pragma unroll
    for (int i = 0; i < 4; ++i) {
        int node = bn + tn * 4 + i;
        float4 o0, o1;
        o0.x = acc[i][0] + b0.x; o0.y = acc[i][1] + b0.y;
        o0.z = acc[i][2] + b0.z; o0.w = acc[i][3] + b0.w;
        o1.x = acc[i][4] + b1.x; o1.y = acc[i][5] + b1.y;
        o1.z = acc[i][6] + b1.z; o1.w = acc[i][7] + b1.w;
        if (do_relu) {
            o0.x = fmaxf(o0.x, 0.f); o0.y = fmaxf(o0.y, 0.f);
            o0.z = fmaxf(o0.z, 0.f); o0.w = fmaxf(o0.w, 0.f);
            o1.x = fmaxf(o1.x, 0.f); o1.y = fmaxf(o1.y, 0.f);
            o1.z = fmaxf(o1.z, 0.f); o1.w = fmaxf(o1.w, 0.f);
        }
        *(float4*)(C + (size_t)node * 128 + c0) = o0;
        *(float4*)(C + (size_t)node * 128 + c1) = o1;
    }
}

// ---------------------------------------------------------------------------
// Attention scores: s_src[n,h] = dot(h2[n,h,:], a_src[h,:]) ; same for dst.
// One wave per node (lane l -> channels l and l+64); 32-lane-group reduction.
// ---------------------------------------------------------------------------
__global__ __launch_bounds__(256) void scores_kernel(const float* __restrict__ h2,
                                                     const float* __restrict__ a_src,
                                                     const float* __restrict__ a_dst,
                                                     float* __restrict__ s_src,
                                                     float* __restrict__ s_dst, int N) {
    int wave = threadIdx.x >> 6, lane = threadIdx.x & 63;
    int n = blockIdx.x * 4 + wave;
    if (n >= N) return;
    int ch0 = lane, ch1 = lane + 64;
    float v0 = h2[(size_t)n * 128 + ch0];
    float v1 = h2[(size_t)n * 128 + ch1];
    float ps0 = v0 * a_src[ch0], ps1 = v1 * a_src[ch1];
    float pd0 = v0 * a_dst[ch0], pd1 = v1 * a_dst[ch1];
#pragma unroll
    for (int m = 1; m < 32; m <<= 1) {
        ps0 += __shfl_xor(ps0, m); ps1 += __shfl_xor(ps1, m);
        pd0 += __shfl_xor(pd0, m); pd1 += __shfl_xor(pd1, m);
    }
    if ((lane & 31) == 0) {
        int hh = lane >> 5;                 // 0 or 1
        s_src[n * 4 + hh]     = ps0;        // heads 0/1 from ch0
        s_src[n * 4 + 2 + hh] = ps1;        // heads 2/3 from ch1
        s_dst[n * 4 + hh]     = pd0;
        s_dst[n * 4 + 2 + hh] = pd1;
    }
}

// ---------------------------------------------------------------------------
// Fused GAT aggregate (online softmax over in-edges) + bias + LayerNorm + ReLU
// + residual. One wave per node; lane l handles channels l and l+64.
// ---------------------------------------------------------------------------
__global__ __launch_bounds__(256) void agg_kernel(const float* __restrict__ h2,
                                                  const float* __restrict__ s_src,
                                                  const float* __restrict__ s_dst,
                                                  const int* __restrict__ rowptr,
                                                  const int* __restrict__ col,
                                                  const float* __restrict__ bg,
                                                  const float* __restrict__ gamma,
                                                  const float* __restrict__ beta,
                                                  const float* __restrict__ res,
                                                  float* __restrict__ out, int N) {
    int wave = threadIdx.x >> 6, lane = threadIdx.x & 63;
    int n = blockIdx.x * 4 + wave;
    if (n >= N) return;
    int ch0 = lane, ch1 = lane + 64;
    int h0 = lane >> 5, h1 = 2 + h0;
    float sd0 = s_dst[n * 4 + h0];
    float sd1 = s_dst[n * 4 + h1];
    int beg = rowptr[n], end = rowptr[n + 1];

    float m0 = -1e30f, m1 = -1e30f, z0 = 0.f, z1 = 0.f, a0 = 0.f, a1 = 0.f;
    for (int j = beg; j < end; ++j) {
        int s = col[j];
        float e0 = s_src[s * 4 + h0] + sd0; e0 = e0 > 0.f ? e0 : 0.2f * e0;
        float e1 = s_src[s * 4 + h1] + sd1; e1 = e1 > 0.f ? e1 : 0.2f * e1;
        float v0 = h2[(size_t)s * 128 + ch0];
        float v1 = h2[(size_t)s * 128 + ch1];
        // one exp per head: t = exp(-|e-m|) serves both rescale and p
        float d0 = e0 - m0;
        float t0 = __expf(-fabsf(d0));
        if (d0 > 0.f) { z0 = z0 * t0 + 1.f; a0 = a0 * t0 + v0; m0 = e0; }
        else          { z0 += t0;           a0 += t0 * v0; }
        float d1 = e1 - m1;
        float t1 = __expf(-fabsf(d1));
        if (d1 > 0.f) { z1 = z1 * t1 + 1.f; a1 = a1 * t1 + v1; m1 = e1; }
        else          { z1 += t1;           a1 += t1 * v1; }
    }
    float o0 = a0 / z0 + bg[ch0];
    float o1 = a1 / z1 + bg[ch1];
    // LayerNorm over 128 channels (wave reduce)
    float s = o0 + o1;
#pragma unroll
    for (int mk = 1; mk < 64; mk <<= 1) s += __shfl_xor(s, mk);
    float mu = s * (1.f / 128.f);
    float q = (o0 - mu) * (o0 - mu) + (o1 - mu) * (o1 - mu);
#pragma unroll
    for (int mk = 1; mk < 64; mk <<= 1) q += __shfl_xor(q, mk);
    float rs = rsqrtf(q * (1.f / 128.f) + LN_EPS);
    float y0 = (o0 - mu) * rs * gamma[ch0] + beta[ch0];
    float y1 = (o1 - mu) * rs * gamma[ch1] + beta[ch1];
    y0 = fmaxf(y0, 0.f) + res[(size_t)n * 128 + ch0];
    y1 = fmaxf(y1, 0.f) + res[(size_t)n * 128 + ch1];
    out[(size_t)n * 128 + ch0] = y0;
    out[(size_t)n * 128 + ch1] = y1;
}

// ---------------------------------------------------------------------------
// Global mean pool (sum + count via atomics); divide happens in classifier.
// ---------------------------------------------------------------------------
__global__ __launch_bounds__(256) void pool_kernel(const float* __restrict__ h,
                                                   const int* __restrict__ batch,
                                                   float* __restrict__ pooled,
                                                   int* __restrict__ cnt, int N, int off) {
    int wave = threadIdx.x >> 6, lane = threadIdx.x & 63;
    int n = blockIdx.x * 4 + wave;
    if (n >= N) return;
    int b = batch[n];
    float v0 = h[(size_t)n * 128 + lane];
    float v1 = h[(size_t)n * 128 + 64 + lane];
    atomicAdd(&pooled[(size_t)b * 256 + off + lane], v0);
    atomicAdd(&pooled[(size_t)b * 256 + off + 64 + lane], v1);
    if (lane == 0) atomicAdd(&cnt[b], 1);
}

// ---------------------------------------------------------------------------
// Classifier MLP: [B,256] -> relu 128 -> relu 64 -> sigmoid 1. Block per row.
// ---------------------------------------------------------------------------
__global__ __launch_bounds__(128) void classifier_kernel(const float* __restrict__ pooled,
                                                         const int* __restrict__ cnt_t,
                                                         const int* __restrict__ cnt_p,
                                                         const float* __restrict__ Wc1,
                                                         const float* __restrict__ bc1,
                                                         const float* __restrict__ Wc2,
                                                         const float* __restrict__ bc2,
                                                         const float* __restrict__ Wc3,
                                                         const float* __restrict__ bc3,
                                                         float* __restrict__ outp) {
    __shared__ float z[256];
    __shared__ float a1[128];
    __shared__ float a2[64];
    int r = blockIdx.x, t = threadIdx.x;
    float ct = (float)max(cnt_t[r], 1);
    float cp = (float)max(cnt_p[r], 1);
    z[t]       = pooled[(size_t)r * 256 + t] / ct;
    z[128 + t] = pooled[(size_t)r * 256 + 128 + t] / cp;
    __syncthreads();
    float acc = bc1[t];
    for (int k = 0; k < 256; ++k) acc = fmaf(z[k], Wc1[k * 128 + t], acc);
    a1[t] = fmaxf(acc, 0.f);
    __syncthreads();
    if (t < 64) {
        float a = bc2[t];
        for (int k = 0; k < 128; ++k) a = fmaf(a1[k], Wc2[k * 64 + t], a);
        a2[t] = fmaxf(a, 0.f);
    }
    __syncthreads();
    if (t < 64) {
        float p = a2[t] * Wc3[t];
#pragma unroll
        for (int mk = 1; mk < 64; mk <<= 1) p += __shfl_xor(p, mk);
        if (t == 0) outp[r] = 1.f / (1.f + __expf(-(p + bc3[0])));
    }
}

// ---------------------------------------------------------------------------
// Host orchestration
// ---------------------------------------------------------------------------
struct GraphBufs {
    float *h_a, *h_b, *h2, *ssrc, *sdst;
    int *rowptr, *cursor, *deg, *col;
};

static void run_graph(const float* x, const int* ei, const int* batch, int N, int E,
                      const float* W_in, const float* b_in, const float* Wg, const float* bg,
                      const float* att_src, const float* att_dst,
                      const float* lng, const float* lnb,
                      float* pooled, int* cnt, int off, const GraphBufs& gb,
                      hipStream_t stream) {
    int tot = E + N;
    hipMemsetAsync(gb.deg, 0, (size_t)N * 4, stream);
    hist_kernel<<<(tot + 255) / 256, 256, 0, stream>>>(ei, gb.deg, E, N);
    scan_kernel<<<1, 1024, 0, stream>>>(gb.deg, gb.rowptr, gb.cursor, N);
    fill_kernel<<<(tot + 255) / 256, 256, 0, stream>>>(ei, gb.cursor, gb.col, E, N);
    // input projection + relu
    gemm128_kernel<<<N / 64, 256, 0, stream>>>(x, W_in, b_in, gb.h_a, N, DIN, 1);
    float* ha = gb.h_a;
    float* hb = gb.h_b;
    for (int i = 0; i < NLAYERS; ++i) {
        gemm128_kernel<<<N / 64, 256, 0, stream>>>(ha, Wg + (size_t)i * HIDDIM * HIDDIM,
                                                   nullptr, gb.h2, N, HIDDIM, 0);
        scores_kernel<<<N / 4, 256, 0, stream>>>(gb.h2, att_src + i * NHEAD * CDIM,
                                                 att_dst + i * NHEAD * CDIM,
                                                 gb.ssrc, gb.sdst, N);
        agg_kernel<<<N / 4, 256, 0, stream>>>(gb.h2, gb.ssrc, gb.sdst, gb.rowptr, gb.col,
                                              bg + i * HIDDIM, lng + i * HIDDIM,
                                              lnb + i * HIDDIM, ha, hb, N);
        float* tmp = ha; ha = hb; hb = tmp;
    }
    pool_kernel<<<N / 4, 256, 0, stream>>>(ha, batch, pooled, cnt, N, off);
}

extern "C" void kernel_launch(void* const* d_in, const int* in_sizes, int n_in,
                              void* d_out, int out_size, void* d_ws, size_t ws_size,
                              hipStream_t stream) {
    const float* tcr_x     = (const float*)d_in[0];
    const int*   tcr_ei    = (const int*)d_in[1];
    const int*   tcr_batch = (const int*)d_in[2];
    const float* pep_x     = (const float*)d_in[3];
    const int*   pep_ei    = (const int*)d_in[4];
    const int*   pep_batch = (const int*)d_in[5];
    const float* W_in      = (const float*)d_in[6];
    const float* b_in      = (const float*)d_in[7];
    const float* Wg        = (const float*)d_in[8];
    const float* bg        = (const float*)d_in[9];
    const float* att_src   = (const float*)d_in[10];
    const float* att_dst   = (const float*)d_in[11];
    const float* ln_gamma  = (const float*)d_in[12];
    const float* ln_beta   = (const float*)d_in[13];
    const float* Wc1       = (const float*)d_in[14];
    const float* bc1       = (const float*)d_in[15];
    const float* Wc2       = (const float*)d_in[16];
    const float* bc2       = (const float*)d_in[17];
    const float* Wc3       = (const float*)d_in[18];
    const float* bc3       = (const float*)d_in[19];

    const int Nt = in_sizes[0] / DIN;
    const int Et = in_sizes[1] / 2;
    const int Np = in_sizes[3] / DIN;
    const int Ep = in_sizes[4] / 2;
    const int B  = out_size;

    const int Nmax = Nt > Np ? Nt : Np;
    const int Etot_max = (Et + Nt) > (Ep + Np) ? (Et + Nt) : (Ep + Np);

    // Workspace layout (single graph-scratch region reused tcr -> pep)
    char* w = (char*)d_ws;
    size_t o = 0;
    auto alloc = [&](size_t bytes) -> char* {
        size_t r = (o + 255) & ~(size_t)255;
        o = r + bytes;
        return w + r;
    };
    float* pooled = (float*)alloc((size_t)B * 256 * 4);
    int*   cnt_t  = (int*)alloc((size_t)B * 4);
    int*   cnt_p  = (int*)alloc((size_t)B * 4);
    GraphBufs gb;
    gb.h_a    = (float*)alloc((size_t)Nmax * 128 * 4);
    gb.h_b    = (float*)alloc((size_t)Nmax * 128 * 4);
    gb.h2     = (float*)alloc((size_t)Nmax * 128 * 4);
    gb.ssrc   = (float*)alloc((size_t)Nmax * 4 * 4);
    gb.sdst   = (float*)alloc((size_t)Nmax * 4 * 4);
    gb.rowptr = (int*)alloc((size_t)(Nmax + 1) * 4);
    gb.cursor = (int*)alloc((size_t)Nmax * 4);
    gb.deg    = (int*)alloc((size_t)Nmax * 4);
    gb.col    = (int*)alloc((size_t)Etot_max * 4);
    (void)ws_size; (void)n_in;

    hipMemsetAsync(pooled, 0, (size_t)B * 256 * 4, stream);
    hipMemsetAsync(cnt_t, 0, (size_t)B * 4, stream);
    hipMemsetAsync(cnt_p, 0, (size_t)B * 4, stream);

    run_graph(tcr_x, tcr_ei, tcr_batch, Nt, Et, W_in, b_in, Wg, bg, att_src, att_dst,
              ln_gamma, ln_beta, pooled, cnt_t, 0, gb, stream);
    run_graph(pep_x, pep_ei, pep_batch, Np, Ep, W_in, b_in, Wg, bg, att_src, att_dst,
              ln_gamma, ln_beta, pooled, cnt_p, 128, gb, stream);

    classifier_kernel<<<B, 128, 0, stream>>>(pooled, cnt_t, cnt_p, Wc1, bc1, Wc2, bc2,
                                             Wc3, bc3, (float*)d_out);
}

// Round 2
// 2197.063 us; speedup vs baseline: 1.1946x; 1.1946x over previous
//
#include <hip/hip_runtime.h>
#include <math.h>

// Problem constants: H=4 heads, C=32, HID=128, 3 layers, B=2048, D=480
#define NHEAD   4
#define CDIM    32
#define HIDDIM  128
#define NLAYERS 3
#define DIN     480
#define LN_EPS  1e-5f

// ---------------------------------------------------------------------------
// Combined-graph CSR build. Node ids: tcr nodes [0,Nt), pep nodes [Nt,Nt+Np).
// Edge list: Et tcr edges, Ep pep edges (+Nt offset), then N self loops.
// ---------------------------------------------------------------------------
__global__ void hist_kernel(const int* __restrict__ tei, const int* __restrict__ pei,
                            int* __restrict__ deg, int Et, int Ep, int Nt, int N) {
    int i = blockIdx.x * 256 + threadIdx.x;
    int tot = Et + Ep + N;
    if (i >= tot) return;
    int d;
    if (i < Et)            d = tei[Et + i];
    else if (i < Et + Ep)  d = pei[Ep + (i - Et)] + Nt;
    else                   d = i - Et - Ep;
    atomicAdd(&deg[d], 1);
}

__global__ void fill_kernel(const int* __restrict__ tei, const int* __restrict__ pei,
                            int* __restrict__ cursor, int* __restrict__ col,
                            int Et, int Ep, int Nt, int N) {
    int i = blockIdx.x * 256 + threadIdx.x;
    int tot = Et + Ep + N;
    if (i >= tot) return;
    int s, d;
    if (i < Et)           { s = tei[i]; d = tei[Et + i]; }
    else if (i < Et + Ep) { int j = i - Et; s = pei[j] + Nt; d = pei[Ep + j] + Nt; }
    else                  { s = d = i - Et - Ep; }
    int pos = atomicAdd(&cursor[d], 1);
    col[pos] = s;
}

// ---------------------------------------------------------------------------
// Hierarchical exclusive scan: 1024 elems per block (int4/thread, coalesced).
// ---------------------------------------------------------------------------
__global__ __launch_bounds__(256) void scan_reduce(const int* __restrict__ deg,
                                                   int* __restrict__ part, int N) {
    __shared__ int sm[256];
    int t = threadIdx.x;
    int base = blockIdx.x * 1024 + t * 4;
    int4 v = make_int4(0, 0, 0, 0);
    if (base + 3 < N) v = *(const int4*)(deg + base);
    else if (base < N) {
        v.x = deg[base];
        if (base + 1 < N) v.y = deg[base + 1];
        if (base + 2 < N) v.z = deg[base + 2];
    }
    sm[t] = v.x + v.y + v.z + v.w;
    __syncthreads();
    for (int off = 128; off >= 1; off >>= 1) {
        if (t < off) sm[t] += sm[t + off];
        __syncthreads();
    }
    if (t == 0) part[blockIdx.x] = sm[0];
}

// One block; exclusive-scans up to 256 block partials in place; writes total.
__global__ __launch_bounds__(256) void scan_partials(int* __restrict__ part,
                                                     int* __restrict__ rowptr,
                                                     int npart, int N) {
    __shared__ int sm[256];
    int t = threadIdx.x;
    sm[t] = (t < npart) ? part[t] : 0;
    __syncthreads();
    for (int off = 1; off < 256; off <<= 1) {
        int u = (t >= off) ? sm[t - off] : 0;
        __syncthreads();
        sm[t] += u;
        __syncthreads();
    }
    if (t < npart) part[t] = (t == 0) ? 0 : sm[t - 1];
    if (t == 0) rowptr[N] = sm[255];
}

__global__ __launch_bounds__(256) void scan_final(const int* __restrict__ deg,
                                                  const int* __restrict__ part,
                                                  int* __restrict__ rowptr,
                                                  int* __restrict__ cursor, int N) {
    __shared__ int sm[256];
    int t = threadIdx.x;
    int base = blockIdx.x * 1024 + t * 4;
    int4 v = make_int4(0, 0, 0, 0);
    if (base + 3 < N) v = *(const int4*)(deg + base);
    else if (base < N) {
        v.x = deg[base];
        if (base + 1 < N) v.y = deg[base + 1];
        if (base + 2 < N) v.z = deg[base + 2];
    }
    sm[t] = v.x + v.y + v.z + v.w;
    __syncthreads();
    for (int off = 1; off < 256; off <<= 1) {
        int u = (t >= off) ? sm[t - off] : 0;
        __syncthreads();
        sm[t] += u;
        __syncthreads();
    }
    int run = ((t == 0) ? 0 : sm[t - 1]) + part[blockIdx.x];
    if (base < N)     { rowptr[base]     = run; cursor[base]     = run; run += v.x; }
    if (base + 1 < N) { rowptr[base + 1] = run; cursor[base + 1] = run; run += v.y; }
    if (base + 2 < N) { rowptr[base + 2] = run; cursor[base + 2] = run; run += v.z; }
    if (base + 3 < N) { rowptr[base + 3] = run; cursor[base + 3] = run; }
}

// ---------------------------------------------------------------------------
// f32 tiled GEMM: C[n,j] = act(sum_k A[n,k]*W[k,j] + bias[j]); 128 output cols.
// Block 256 thr, tile 64 nodes x 128 cols, Kt=16. Requires N%64==0, K%16==0.
// ---------------------------------------------------------------------------
__global__ __launch_bounds__(256) void gemm128_kernel(const float* __restrict__ A,
                                                      const float* __restrict__ W,
                                                      const float* __restrict__ bias,
                                                      float* __restrict__ C,
                                                      int N, int K, int do_relu) {
    __shared__ float As[64 * 17];
    __shared__ float Ws[16 * 128];
    const int tid = threadIdx.x;
    const int bn  = blockIdx.x * 64;
    const int tj  = tid & 15;
    const int tn  = tid >> 4;
    const int c0  = tj * 4;
    const int c1  = 64 + tj * 4;

    float acc[4][8];
#pragma unroll
    for (int i = 0; i < 4; ++i)
#pragma unroll
        for (int u = 0; u < 8; ++u) acc[i][u] = 0.f;

    const int la_c  = tid & 15;
    const int la_r0 = tid >> 4;

    for (int kt = 0; kt < K; kt += 16) {
#pragma unroll
        for (int p = 0; p < 4; ++p) {
            int r = la_r0 + p * 16;
            As[r * 17 + la_c] = A[(size_t)(bn + r) * K + kt + la_c];
        }
        {
            const float4* Wv  = (const float4*)(W + (size_t)kt * 128);
            float4*       Wsv = (float4*)Ws;
            Wsv[tid * 2]     = Wv[tid * 2];
            Wsv[tid * 2 + 1] = Wv[tid * 2 + 1];
        }
        __syncthreads();
#pragma unroll
        for (int kk = 0; kk < 16; ++kk) {
            float av[4];
#pragma unroll
            for (int i = 0; i < 4; ++i) av[i] = As[(tn * 4 + i) * 17 + kk];
            const float* wr = Ws + kk * 128;
            float4 w0 = *(const float4*)(wr + c0);
            float4 w1 = *(const float4*)(wr + c1);
            float wv[8] = {w0.x, w0.y, w0.z, w0.w, w1.x, w1.y, w1.z, w1.w};
#pragma unroll
            for (int i = 0; i < 4; ++i)
#pragma unroll
                for (int u = 0; u < 8; ++u)
                    acc[i][u] = fmaf(av[i], wv[u], acc[i][u]);
        }
        __syncthreads();
    }

    float4 b0 = make_float4(0.f, 0.f, 0.f, 0.f), b1 = b0;
    if (bias) { b0 = *(const float4*)(bias + c0); b1 = *(const float4*)(bias + c1); }
#pragma unroll
    for (int i = 0; i < 4; ++i) {
        int node = bn + tn * 4 + i;
        float4 o0, o1;
        o0.x = acc[i][0] + b0.x; o0.y = acc[i][1] + b0.y;
        o0.z = acc[i][2] + b0.z; o0.w = acc[i][3] + b0.w;
        o1.x = acc[i][4] + b1.x; o1.y = acc[i][5] + b1.y;
        o1.z = acc[i][6] + b1.z; o1.w = acc[i][7] + b1.w;
        if (do_relu) {
            o0.x = fmaxf(o0.x, 0.f); o0.y = fmaxf(o0.y, 0.f);
            o0.z = fmaxf(o0.z, 0.f); o0.w = fmaxf(o0.w, 0.f);
            o1.x = fmaxf(o1.x, 0.f); o1.y = fmaxf(o1.y, 0.f);
            o1.z = fmaxf(o1.z, 0.f); o1.w = fmaxf(o1.w, 0.f);
        }
        *(float4*)(C + (size_t)node * 128 + c0) = o0;
        *(float4*)(C + (size_t)node * 128 + c1) = o1;
    }
}

// ---------------------------------------------------------------------------
// Attention scores: one wave per node; lane l -> channels l and l+64.
// ---------------------------------------------------------------------------
__global__ __launch_bounds__(256) void scores_kernel(const float* __restrict__ h2,
                                                     const float* __restrict__ a_src,
                                                     const float* __restrict__ a_dst,
                                                     float* __restrict__ s_src,
                                                     float* __restrict__ s_dst, int N) {
    int wave = threadIdx.x >> 6, lane = threadIdx.x & 63;
    int n = blockIdx.x * 4 + wave;
    if (n >= N) return;
    int ch0 = lane, ch1 = lane + 64;
    float v0 = h2[(size_t)n * 128 + ch0];
    float v1 = h2[(size_t)n * 128 + ch1];
    float ps0 = v0 * a_src[ch0], ps1 = v1 * a_src[ch1];
    float pd0 = v0 * a_dst[ch0], pd1 = v1 * a_dst[ch1];
#pragma unroll
    for (int m = 1; m < 32; m <<= 1) {
        ps0 += __shfl_xor(ps0, m); ps1 += __shfl_xor(ps1, m);
        pd0 += __shfl_xor(pd0, m); pd1 += __shfl_xor(pd1, m);
    }
    if ((lane & 31) == 0) {
        int hh = lane >> 5;
        s_src[n * 4 + hh]     = ps0;
        s_src[n * 4 + 2 + hh] = ps1;
        s_dst[n * 4 + hh]     = pd0;
        s_dst[n * 4 + 2 + hh] = pd1;
    }
}

// ---------------------------------------------------------------------------
// Fused GAT aggregate (online softmax) + bias + LayerNorm + ReLU + residual.
// ---------------------------------------------------------------------------
__global__ __launch_bounds__(256) void agg_kernel(const float* __restrict__ h2,
                                                  const float* __restrict__ s_src,
                                                  const float* __restrict__ s_dst,
                                                  const int* __restrict__ rowptr,
                                                  const int* __restrict__ col,
                                                  const float* __restrict__ bg,
                                                  const float* __restrict__ gamma,
                                                  const float* __restrict__ beta,
                                                  const float* __restrict__ res,
                                                  float* __restrict__ out, int N) {
    int wave = threadIdx.x >> 6, lane = threadIdx.x & 63;
    int n = blockIdx.x * 4 + wave;
    if (n >= N) return;
    int ch0 = lane, ch1 = lane + 64;
    int h0 = lane >> 5, h1 = 2 + h0;
    float sd0 = s_dst[n * 4 + h0];
    float sd1 = s_dst[n * 4 + h1];
    int beg = rowptr[n], end = rowptr[n + 1];

    float m0 = -1e30f, m1 = -1e30f, z0 = 0.f, z1 = 0.f, a0 = 0.f, a1 = 0.f;
    for (int j = beg; j < end; ++j) {
        int s = col[j];
        float e0 = s_src[s * 4 + h0] + sd0; e0 = e0 > 0.f ? e0 : 0.2f * e0;
        float e1 = s_src[s * 4 + h1] + sd1; e1 = e1 > 0.f ? e1 : 0.2f * e1;
        float v0 = h2[(size_t)s * 128 + ch0];
        float v1 = h2[(size_t)s * 128 + ch1];
        float d0 = e0 - m0;
        float t0 = __expf(-fabsf(d0));
        if (d0 > 0.f) { z0 = z0 * t0 + 1.f; a0 = a0 * t0 + v0; m0 = e0; }
        else          { z0 += t0;           a0 += t0 * v0; }
        float d1 = e1 - m1;
        float t1 = __expf(-fabsf(d1));
        if (d1 > 0.f) { z1 = z1 * t1 + 1.f; a1 = a1 * t1 + v1; m1 = e1; }
        else          { z1 += t1;           a1 += t1 * v1; }
    }
    float o0 = a0 / z0 + bg[ch0];
    float o1 = a1 / z1 + bg[ch1];
    float s = o0 + o1;
#pragma unroll
    for (int mk = 1; mk < 64; mk <<= 1) s += __shfl_xor(s, mk);
    float mu = s * (1.f / 128.f);
    float q = (o0 - mu) * (o0 - mu) + (o1 - mu) * (o1 - mu);
#pragma unroll
    for (int mk = 1; mk < 64; mk <<= 1) q += __shfl_xor(q, mk);
    float rs = rsqrtf(q * (1.f / 128.f) + LN_EPS);
    float y0 = (o0 - mu) * rs * gamma[ch0] + beta[ch0];
    float y1 = (o1 - mu) * rs * gamma[ch1] + beta[ch1];
    y0 = fmaxf(y0, 0.f) + res[(size_t)n * 128 + ch0];
    y1 = fmaxf(y1, 0.f) + res[(size_t)n * 128 + ch1];
    out[(size_t)n * 128 + ch0] = y0;
    out[(size_t)n * 128 + ch1] = y1;
}

// ---------------------------------------------------------------------------
// Global mean pool over combined nodes. tcr -> pooled[b][0:128], cnt[b];
// pep -> pooled[b][128:256], cnt[B+b].
// ---------------------------------------------------------------------------
__global__ __launch_bounds__(256) void pool_kernel(const float* __restrict__ h,
                                                   const int* __restrict__ tb,
                                                   const int* __restrict__ pb,
                                                   float* __restrict__ pooled,
                                                   int* __restrict__ cnt,
                                                   int Nt, int N, int B) {
    int wave = threadIdx.x >> 6, lane = threadIdx.x & 63;
    int n = blockIdx.x * 4 + wave;
    if (n >= N) return;
    int b, off, ci;
    if (n < Nt) { b = tb[n];      off = 0;   ci = b; }
    else        { b = pb[n - Nt]; off = 128; ci = B + b; }
    float v0 = h[(size_t)n * 128 + lane];
    float v1 = h[(size_t)n * 128 + 64 + lane];
    atomicAdd(&pooled[(size_t)b * 256 + off + lane], v0);
    atomicAdd(&pooled[(size_t)b * 256 + off + 64 + lane], v1);
    if (lane == 0) atomicAdd(&cnt[ci], 1);
}

// ---------------------------------------------------------------------------
// Classifier MLP: [B,256] -> relu 128 -> relu 64 -> sigmoid 1. Block per row.
// ---------------------------------------------------------------------------
__global__ __launch_bounds__(128) void classifier_kernel(const float* __restrict__ pooled,
                                                         const int* __restrict__ cnt,
                                                         const float* __restrict__ Wc1,
                                                         const float* __restrict__ bc1,
                                                         const float* __restrict__ Wc2,
                                                         const float* __restrict__ bc2,
                                                         const float* __restrict__ Wc3,
                                                         const float* __restrict__ bc3,
                                                         float* __restrict__ outp, int B) {
    __shared__ float z[256];
    __shared__ float a1[128];
    __shared__ float a2[64];
    int r = blockIdx.x, t = threadIdx.x;
    float ct = (float)max(cnt[r], 1);
    float cp = (float)max(cnt[B + r], 1);
    z[t]       = pooled[(size_t)r * 256 + t] / ct;
    z[128 + t] = pooled[(size_t)r * 256 + 128 + t] / cp;
    __syncthreads();
    float acc = bc1[t];
    for (int k = 0; k < 256; ++k) acc = fmaf(z[k], Wc1[k * 128 + t], acc);
    a1[t] = fmaxf(acc, 0.f);
    __syncthreads();
    if (t < 64) {
        float a = bc2[t];
        for (int k = 0; k < 128; ++k) a = fmaf(a1[k], Wc2[k * 64 + t], a);
        a2[t] = fmaxf(a, 0.f);
    }
    __syncthreads();
    if (t < 64) {
        float p = a2[t] * Wc3[t];
#pragma unroll
        for (int mk = 1; mk < 64; mk <<= 1) p += __shfl_xor(p, mk);
        if (t == 0) outp[r] = 1.f / (1.f + __expf(-(p + bc3[0])));
    }
}

// ---------------------------------------------------------------------------
// Host orchestration — single combined graph.
// ---------------------------------------------------------------------------
extern "C" void kernel_launch(void* const* d_in, const int* in_sizes, int n_in,
                              void* d_out, int out_size, void* d_ws, size_t ws_size,
                              hipStream_t stream) {
    const float* tcr_x     = (const float*)d_in[0];
    const int*   tcr_ei    = (const int*)d_in[1];
    const int*   tcr_batch = (const int*)d_in[2];
    const float* pep_x     = (const float*)d_in[3];
    const int*   pep_ei    = (const int*)d_in[4];
    const int*   pep_batch = (const int*)d_in[5];
    const float* W_in      = (const float*)d_in[6];
    const float* b_in      = (const float*)d_in[7];
    const float* Wg        = (const float*)d_in[8];
    const float* bg        = (const float*)d_in[9];
    const float* att_src   = (const float*)d_in[10];
    const float* att_dst   = (const float*)d_in[11];
    const float* ln_gamma  = (const float*)d_in[12];
    const float* ln_beta   = (const float*)d_in[13];
    const float* Wc1       = (const float*)d_in[14];
    const float* bc1       = (const float*)d_in[15];
    const float* Wc2       = (const float*)d_in[16];
    const float* bc2       = (const float*)d_in[17];
    const float* Wc3       = (const float*)d_in[18];
    const float* bc3       = (const float*)d_in[19];

    const int Nt = in_sizes[0] / DIN;
    const int Et = in_sizes[1] / 2;
    const int Np = in_sizes[3] / DIN;
    const int Ep = in_sizes[4] / 2;
    const int B  = out_size;
    const int N  = Nt + Np;          // combined nodes
    const int Etot = Et + Ep + N;    // edges + self loops

    char* w = (char*)d_ws;
    size_t o = 0;
    auto alloc = [&](size_t bytes) -> char* {
        size_t r = (o + 255) & ~(size_t)255;
        o = r + bytes;
        return w + r;
    };
    float* pooled = (float*)alloc((size_t)B * 256 * 4);
    int*   cnt    = (int*)alloc((size_t)B * 2 * 4);
    float* h_a    = (float*)alloc((size_t)N * 128 * 4);
    float* h_b    = (float*)alloc((size_t)N * 128 * 4);
    float* h2     = (float*)alloc((size_t)N * 128 * 4);
    float* ssrc   = (float*)alloc((size_t)N * 4 * 4);
    float* sdst   = (float*)alloc((size_t)N * 4 * 4);
    int* rowptr   = (int*)alloc((size_t)(N + 1) * 4);
    int* cursor   = (int*)alloc((size_t)N * 4);
    int* deg      = (int*)alloc((size_t)N * 4);
    int* part     = (int*)alloc(256 * 4);
    int* col      = (int*)alloc((size_t)Etot * 4);
    (void)ws_size; (void)n_in;

    hipMemsetAsync(pooled, 0, (size_t)B * 256 * 4, stream);
    hipMemsetAsync(cnt, 0, (size_t)B * 2 * 4, stream);
    hipMemsetAsync(deg, 0, (size_t)N * 4, stream);

    // CSR build (combined)
    hist_kernel<<<(Etot + 255) / 256, 256, 0, stream>>>(tcr_ei, pep_ei, deg, Et, Ep, Nt, N);
    int nblk = (N + 1023) / 1024;
    scan_reduce<<<nblk, 256, 0, stream>>>(deg, part, N);
    scan_partials<<<1, 256, 0, stream>>>(part, rowptr, nblk, N);
    scan_final<<<nblk, 256, 0, stream>>>(deg, part, rowptr, cursor, N);
    fill_kernel<<<(Etot + 255) / 256, 256, 0, stream>>>(tcr_ei, pep_ei, cursor, col, Et, Ep, Nt, N);

    // Input projection + relu (two x arrays -> one combined h_a)
    gemm128_kernel<<<Nt / 64, 256, 0, stream>>>(tcr_x, W_in, b_in, h_a, Nt, DIN, 1);
    gemm128_kernel<<<Np / 64, 256, 0, stream>>>(pep_x, W_in, b_in, h_a + (size_t)Nt * 128, Np, DIN, 1);

    float* ha = h_a;
    float* hb = h_b;
    for (int i = 0; i < NLAYERS; ++i) {
        gemm128_kernel<<<N / 64, 256, 0, stream>>>(ha, Wg + (size_t)i * HIDDIM * HIDDIM,
                                                   nullptr, h2, N, HIDDIM, 0);
        scores_kernel<<<(N + 3) / 4, 256, 0, stream>>>(h2, att_src + i * NHEAD * CDIM,
                                                       att_dst + i * NHEAD * CDIM,
                                                       ssrc, sdst, N);
        agg_kernel<<<(N + 3) / 4, 256, 0, stream>>>(h2, ssrc, sdst, rowptr, col,
                                                    bg + i * HIDDIM, ln_gamma + i * HIDDIM,
                                                    ln_beta + i * HIDDIM, ha, hb, N);
        float* tmp = ha; ha = hb; hb = tmp;
    }
    pool_kernel<<<(N + 3) / 4, 256, 0, stream>>>(ha, tcr_batch, pep_batch, pooled, cnt, Nt, N, B);

    classifier_kernel<<<B, 128, 0, stream>>>(pooled, cnt, Wc1, bc1, Wc2, bc2,
                                             Wc3, bc3, (float*)d_out, B);
}

// Round 3
// 2114.734 us; speedup vs baseline: 1.2411x; 1.0389x over previous
//
#include <hip/hip_runtime.h>
#include <hip/hip_fp16.h>
#include <math.h>

// Problem constants: H=4 heads, C=32, HID=128, 3 layers, B=2048, D=480
#define NHEAD   4
#define CDIM    32
#define HIDDIM  128
#define NLAYERS 3
#define DIN     480
#define LN_EPS  1e-5f

// ---------------------------------------------------------------------------
// Combined-graph CSR build. Node ids: tcr [0,Nt), pep [Nt,Nt+Np).
// ---------------------------------------------------------------------------
__global__ void hist_kernel(const int* __restrict__ tei, const int* __restrict__ pei,
                            int* __restrict__ deg, int Et, int Ep, int Nt, int N) {
    int i = blockIdx.x * 256 + threadIdx.x;
    int tot = Et + Ep + N;
    if (i >= tot) return;
    int d;
    if (i < Et)            d = tei[Et + i];
    else if (i < Et + Ep)  d = pei[Ep + (i - Et)] + Nt;
    else                   d = i - Et - Ep;
    atomicAdd(&deg[d], 1);
}

__global__ void fill_kernel(const int* __restrict__ tei, const int* __restrict__ pei,
                            int* __restrict__ cursor, int* __restrict__ col,
                            int Et, int Ep, int Nt, int N) {
    int i = blockIdx.x * 256 + threadIdx.x;
    int tot = Et + Ep + N;
    if (i >= tot) return;
    int s, d;
    if (i < Et)           { s = tei[i]; d = tei[Et + i]; }
    else if (i < Et + Ep) { int j = i - Et; s = pei[j] + Nt; d = pei[Ep + j] + Nt; }
    else                  { s = d = i - Et - Ep; }
    int pos = atomicAdd(&cursor[d], 1);
    col[pos] = s;
}

// ---------------------------------------------------------------------------
// Hierarchical exclusive scan: 1024 elems/block, int4 coalesced.
// ---------------------------------------------------------------------------
__global__ __launch_bounds__(256) void scan_reduce(const int* __restrict__ deg,
                                                   int* __restrict__ part, int N) {
    __shared__ int sm[256];
    int t = threadIdx.x;
    int base = blockIdx.x * 1024 + t * 4;
    int4 v = make_int4(0, 0, 0, 0);
    if (base + 3 < N) v = *(const int4*)(deg + base);
    else if (base < N) {
        v.x = deg[base];
        if (base + 1 < N) v.y = deg[base + 1];
        if (base + 2 < N) v.z = deg[base + 2];
    }
    sm[t] = v.x + v.y + v.z + v.w;
    __syncthreads();
    for (int off = 128; off >= 1; off >>= 1) {
        if (t < off) sm[t] += sm[t + off];
        __syncthreads();
    }
    if (t == 0) part[blockIdx.x] = sm[0];
}

__global__ __launch_bounds__(256) void scan_partials(int* __restrict__ part,
                                                     int* __restrict__ rowptr,
                                                     int npart, int N) {
    __shared__ int sm[256];
    int t = threadIdx.x;
    sm[t] = (t < npart) ? part[t] : 0;
    __syncthreads();
    for (int off = 1; off < 256; off <<= 1) {
        int u = (t >= off) ? sm[t - off] : 0;
        __syncthreads();
        sm[t] += u;
        __syncthreads();
    }
    if (t < npart) part[t] = (t == 0) ? 0 : sm[t - 1];
    if (t == 0) rowptr[N] = sm[255];
}

__global__ __launch_bounds__(256) void scan_final(const int* __restrict__ deg,
                                                  const int* __restrict__ part,
                                                  int* __restrict__ rowptr,
                                                  int* __restrict__ cursor, int N) {
    __shared__ int sm[256];
    int t = threadIdx.x;
    int base = blockIdx.x * 1024 + t * 4;
    int4 v = make_int4(0, 0, 0, 0);
    if (base + 3 < N) v = *(const int4*)(deg + base);
    else if (base < N) {
        v.x = deg[base];
        if (base + 1 < N) v.y = deg[base + 1];
        if (base + 2 < N) v.z = deg[base + 2];
    }
    sm[t] = v.x + v.y + v.z + v.w;
    __syncthreads();
    for (int off = 1; off < 256; off <<= 1) {
        int u = (t >= off) ? sm[t - off] : 0;
        __syncthreads();
        sm[t] += u;
        __syncthreads();
    }
    int run = ((t == 0) ? 0 : sm[t - 1]) + part[blockIdx.x];
    if (base < N)     { rowptr[base]     = run; cursor[base]     = run; run += v.x; }
    if (base + 1 < N) { rowptr[base + 1] = run; cursor[base + 1] = run; run += v.y; }
    if (base + 2 < N) { rowptr[base + 2] = run; cursor[base + 2] = run; run += v.z; }
    if (base + 3 < N) { rowptr[base + 3] = run; cursor[base + 3] = run; }
}

// ---------------------------------------------------------------------------
// f32 tiled GEMM (f32 out, bias+relu) — used for the input projection K=480.
// ---------------------------------------------------------------------------
__global__ __launch_bounds__(256) void gemm128_f32(const float* __restrict__ A,
                                                   const float* __restrict__ W,
                                                   const float* __restrict__ bias,
                                                   float* __restrict__ C,
                                                   int N, int K) {
    __shared__ float As[64 * 17];
    __shared__ float Ws[16 * 128];
    const int tid = threadIdx.x;
    const int bn  = blockIdx.x * 64;
    const int tj  = tid & 15;
    const int tn  = tid >> 4;
    const int c0  = tj * 4;
    const int c1  = 64 + tj * 4;

    float acc[4][8];
#pragma unroll
    for (int i = 0; i < 4; ++i)
#pragma unroll
        for (int u = 0; u < 8; ++u) acc[i][u] = 0.f;

    const int la_c  = tid & 15;
    const int la_r0 = tid >> 4;

    for (int kt = 0; kt < K; kt += 16) {
#pragma unroll
        for (int p = 0; p < 4; ++p) {
            int r = la_r0 + p * 16;
            As[r * 17 + la_c] = A[(size_t)(bn + r) * K + kt + la_c];
        }
        {
            const float4* Wv  = (const float4*)(W + (size_t)kt * 128);
            float4*       Wsv = (float4*)Ws;
            Wsv[tid * 2]     = Wv[tid * 2];
            Wsv[tid * 2 + 1] = Wv[tid * 2 + 1];
        }
        __syncthreads();
#pragma unroll
        for (int kk = 0; kk < 16; ++kk) {
            float av[4];
#pragma unroll
            for (int i = 0; i < 4; ++i) av[i] = As[(tn * 4 + i) * 17 + kk];
            const float* wr = Ws + kk * 128;
            float4 w0 = *(const float4*)(wr + c0);
            float4 w1 = *(const float4*)(wr + c1);
            float wv[8] = {w0.x, w0.y, w0.z, w0.w, w1.x, w1.y, w1.z, w1.w};
#pragma unroll
            for (int i = 0; i < 4; ++i)
#pragma unroll
                for (int u = 0; u < 8; ++u)
                    acc[i][u] = fmaf(av[i], wv[u], acc[i][u]);
        }
        __syncthreads();
    }

    float4 b0 = *(const float4*)(bias + c0);
    float4 b1 = *(const float4*)(bias + c1);
#pragma unroll
    for (int i = 0; i < 4; ++i) {
        int node = bn + tn * 4 + i;
        float4 o0, o1;
        o0.x = fmaxf(acc[i][0] + b0.x, 0.f); o0.y = fmaxf(acc[i][1] + b0.y, 0.f);
        o0.z = fmaxf(acc[i][2] + b0.z, 0.f); o0.w = fmaxf(acc[i][3] + b0.w, 0.f);
        o1.x = fmaxf(acc[i][4] + b1.x, 0.f); o1.y = fmaxf(acc[i][5] + b1.y, 0.f);
        o1.z = fmaxf(acc[i][6] + b1.z, 0.f); o1.w = fmaxf(acc[i][7] + b1.w, 0.f);
        *(float4*)(C + (size_t)node * 128 + c0) = o0;
        *(float4*)(C + (size_t)node * 128 + c1) = o1;
    }
}

// ---------------------------------------------------------------------------
// f32 GEMM with fp16 output, no bias/act — layer projection h2 = h @ Wg.
// ---------------------------------------------------------------------------
__global__ __launch_bounds__(256) void gemm128_f16(const float* __restrict__ A,
                                                   const float* __restrict__ W,
                                                   __half* __restrict__ C,
                                                   int N, int K) {
    __shared__ float As[64 * 17];
    __shared__ float Ws[16 * 128];
    const int tid = threadIdx.x;
    const int bn  = blockIdx.x * 64;
    const int tj  = tid & 15;
    const int tn  = tid >> 4;
    const int c0  = tj * 4;
    const int c1  = 64 + tj * 4;

    float acc[4][8];
#pragma unroll
    for (int i = 0; i < 4; ++i)
#pragma unroll
        for (int u = 0; u < 8; ++u) acc[i][u] = 0.f;

    const int la_c  = tid & 15;
    const int la_r0 = tid >> 4;

    for (int kt = 0; kt < K; kt += 16) {
#pragma unroll
        for (int p = 0; p < 4; ++p) {
            int r = la_r0 + p * 16;
            As[r * 17 + la_c] = A[(size_t)(bn + r) * K + kt + la_c];
        }
        {
            const float4* Wv  = (const float4*)(W + (size_t)kt * 128);
            float4*       Wsv = (float4*)Ws;
            Wsv[tid * 2]     = Wv[tid * 2];
            Wsv[tid * 2 + 1] = Wv[tid * 2 + 1];
        }
        __syncthreads();
#pragma unroll
        for (int kk = 0; kk < 16; ++kk) {
            float av[4];
#pragma unroll
            for (int i = 0; i < 4; ++i) av[i] = As[(tn * 4 + i) * 17 + kk];
            const float* wr = Ws + kk * 128;
            float4 w0 = *(const float4*)(wr + c0);
            float4 w1 = *(const float4*)(wr + c1);
            float wv[8] = {w0.x, w0.y, w0.z, w0.w, w1.x, w1.y, w1.z, w1.w};
#pragma unroll
            for (int i = 0; i < 4; ++i)
#pragma unroll
                for (int u = 0; u < 8; ++u)
                    acc[i][u] = fmaf(av[i], wv[u], acc[i][u]);
        }
        __syncthreads();
    }

#pragma unroll
    for (int i = 0; i < 4; ++i) {
        int node = bn + tn * 4 + i;
        __half* d0 = C + (size_t)node * 128 + c0;
        __half* d1 = C + (size_t)node * 128 + c1;
        *(__half2*)(d0)     = __floats2half2_rn(acc[i][0], acc[i][1]);
        *(__half2*)(d0 + 2) = __floats2half2_rn(acc[i][2], acc[i][3]);
        *(__half2*)(d1)     = __floats2half2_rn(acc[i][4], acc[i][5]);
        *(__half2*)(d1 + 2) = __floats2half2_rn(acc[i][6], acc[i][7]);
    }
}

// ---------------------------------------------------------------------------
// Attention scores from fp16 h2. One wave per node; lane l -> ch 2l,2l+1,
// head = l>>4. 16-lane group reduction -> s_src[n*4+h], s_dst[n*4+h].
// ---------------------------------------------------------------------------
__global__ __launch_bounds__(256) void scores_kernel(const __half2* __restrict__ h2v,
                                                     const float* __restrict__ a_src,
                                                     const float* __restrict__ a_dst,
                                                     float* __restrict__ ssrc,
                                                     float* __restrict__ sdst, int N) {
    int wave = threadIdx.x >> 6, lane = threadIdx.x & 63;
    int n = blockIdx.x * 4 + wave;
    if (n >= N) return;
    int c = lane * 2, h = lane >> 4, t = lane & 15;
    float2 v = __half22float2(h2v[(size_t)n * 64 + lane]);
    float2 as = *(const float2*)(a_src + c);
    float2 ad = *(const float2*)(a_dst + c);
    float ps = v.x * as.x + v.y * as.y;
    float pd = v.x * ad.x + v.y * ad.y;
#pragma unroll
    for (int k = 1; k < 16; k <<= 1) {
        ps += __shfl_xor(ps, k, 16);
        pd += __shfl_xor(pd, k, 16);
    }
    if (t == 0) {
        ssrc[n * 4 + h] = ps;
        sdst[n * 4 + h] = pd;
    }
}

// ---------------------------------------------------------------------------
// Phase 1: per-edge softmax weights. 16 lanes per node, 4 nodes per wave.
// Writes unnormalized p[E][4] and z[N][4].
// ---------------------------------------------------------------------------
__global__ __launch_bounds__(256) void alpha_kernel(const float4* __restrict__ ssrc4,
                                                    const float4* __restrict__ sdst4,
                                                    const int* __restrict__ rowptr,
                                                    const int* __restrict__ col,
                                                    float4* __restrict__ alpha4,
                                                    float4* __restrict__ zbuf4, int N) {
    int wave = threadIdx.x >> 6, lane = threadIdx.x & 63;
    int g = lane >> 4, t = lane & 15;
    int n = blockIdx.x * 16 + wave * 4 + g;
    bool valid = n < N;
    int nn = valid ? n : 0;
    float4 sd = sdst4[nn];
    int beg = valid ? rowptr[nn] : 0;
    int end = valid ? rowptr[nn + 1] : 0;

    float m0 = -1e30f, m1 = -1e30f, m2 = -1e30f, m3 = -1e30f;
    for (int j = beg + t; j < end; j += 16) {
        int s = col[j];
        float4 ss = ssrc4[s];
        float e0 = ss.x + sd.x; e0 = e0 > 0.f ? e0 : 0.2f * e0;
        float e1 = ss.y + sd.y; e1 = e1 > 0.f ? e1 : 0.2f * e1;
        float e2 = ss.z + sd.z; e2 = e2 > 0.f ? e2 : 0.2f * e2;
        float e3 = ss.w + sd.w; e3 = e3 > 0.f ? e3 : 0.2f * e3;
        alpha4[j] = make_float4(e0, e1, e2, e3);
        m0 = fmaxf(m0, e0); m1 = fmaxf(m1, e1);
        m2 = fmaxf(m2, e2); m3 = fmaxf(m3, e3);
    }
#pragma unroll
    for (int k = 1; k < 16; k <<= 1) {
        m0 = fmaxf(m0, __shfl_xor(m0, k, 16));
        m1 = fmaxf(m1, __shfl_xor(m1, k, 16));
        m2 = fmaxf(m2, __shfl_xor(m2, k, 16));
        m3 = fmaxf(m3, __shfl_xor(m3, k, 16));
    }
    float z0 = 0.f, z1 = 0.f, z2 = 0.f, z3 = 0.f;
    for (int j = beg + t; j < end; j += 16) {
        float4 e = alpha4[j];
        float p0 = __expf(e.x - m0);
        float p1 = __expf(e.y - m1);
        float p2 = __expf(e.z - m2);
        float p3 = __expf(e.w - m3);
        alpha4[j] = make_float4(p0, p1, p2, p3);
        z0 += p0; z1 += p1; z2 += p2; z3 += p3;
    }
#pragma unroll
    for (int k = 1; k < 16; k <<= 1) {
        z0 += __shfl_xor(z0, k, 16);
        z1 += __shfl_xor(z1, k, 16);
        z2 += __shfl_xor(z2, k, 16);
        z3 += __shfl_xor(z3, k, 16);
    }
    if (valid && t == 0) zbuf4[nn] = make_float4(z0, z1, z2, z3);
}

// ---------------------------------------------------------------------------
// Phase 2: lean gather  a += p * v  (fp16 values), then /z + bias + LayerNorm
// + ReLU + residual, in place. One wave per node; lane l -> ch 2l,2l+1.
// ---------------------------------------------------------------------------
__global__ __launch_bounds__(256) void gather_kernel(const __half2* __restrict__ h2v,
                                                     const float* __restrict__ alphaF,
                                                     const float* __restrict__ zF,
                                                     const int* __restrict__ rowptr,
                                                     const int* __restrict__ col,
                                                     const float* __restrict__ bg,
                                                     const float* __restrict__ gamma,
                                                     const float* __restrict__ beta,
                                                     float* __restrict__ hio, int N) {
    int wave = threadIdx.x >> 6, lane = threadIdx.x & 63;
    int n = blockIdx.x * 4 + wave;
    if (n >= N) return;
    int c = lane * 2, h = lane >> 4;
    int beg = rowptr[n], end = rowptr[n + 1];
    float a0 = 0.f, a1 = 0.f;
    for (int j = beg; j < end; ++j) {
        int s = col[j];
        float p = alphaF[j * 4 + h];
        float2 v = __half22float2(h2v[(size_t)s * 64 + lane]);
        a0 = fmaf(p, v.x, a0);
        a1 = fmaf(p, v.y, a1);
    }
    float inv = 1.f / zF[n * 4 + h];
    float2 bgv = *(const float2*)(bg + c);
    float o0 = a0 * inv + bgv.x;
    float o1 = a1 * inv + bgv.y;
    float s = o0 + o1;
#pragma unroll
    for (int k = 1; k < 64; k <<= 1) s += __shfl_xor(s, k);
    float mu = s * (1.f / 128.f);
    float q = (o0 - mu) * (o0 - mu) + (o1 - mu) * (o1 - mu);
#pragma unroll
    for (int k = 1; k < 64; k <<= 1) q += __shfl_xor(q, k);
    float rs = rsqrtf(q * (1.f / 128.f) + LN_EPS);
    float2 gm = *(const float2*)(gamma + c);
    float2 bt = *(const float2*)(beta + c);
    float y0 = (o0 - mu) * rs * gm.x + bt.x;
    float y1 = (o1 - mu) * rs * gm.y + bt.y;
    float2 r = *(const float2*)(hio + (size_t)n * 128 + c);
    y0 = fmaxf(y0, 0.f) + r.x;
    y1 = fmaxf(y1, 0.f) + r.y;
    *(float2*)(hio + (size_t)n * 128 + c) = make_float2(y0, y1);
}

// ---------------------------------------------------------------------------
// Global mean pool. tcr -> pooled[b][0:128], cnt[b]; pep -> [128:256], cnt[B+b].
// ---------------------------------------------------------------------------
__global__ __launch_bounds__(256) void pool_kernel(const float* __restrict__ h,
                                                   const int* __restrict__ tb,
                                                   const int* __restrict__ pb,
                                                   float* __restrict__ pooled,
                                                   int* __restrict__ cnt,
                                                   int Nt, int N, int B) {
    int wave = threadIdx.x >> 6, lane = threadIdx.x & 63;
    int n = blockIdx.x * 4 + wave;
    if (n >= N) return;
    int b, off, ci;
    if (n < Nt) { b = tb[n];      off = 0;   ci = b; }
    else        { b = pb[n - Nt]; off = 128; ci = B + b; }
    float v0 = h[(size_t)n * 128 + lane];
    float v1 = h[(size_t)n * 128 + 64 + lane];
    atomicAdd(&pooled[(size_t)b * 256 + off + lane], v0);
    atomicAdd(&pooled[(size_t)b * 256 + off + 64 + lane], v1);
    if (lane == 0) atomicAdd(&cnt[ci], 1);
}

// ---------------------------------------------------------------------------
// Classifier MLP: [B,256] -> relu 128 -> relu 64 -> sigmoid 1. Block per row.
// ---------------------------------------------------------------------------
__global__ __launch_bounds__(128) void classifier_kernel(const float* __restrict__ pooled,
                                                         const int* __restrict__ cnt,
                                                         const float* __restrict__ Wc1,
                                                         const float* __restrict__ bc1,
                                                         const float* __restrict__ Wc2,
                                                         const float* __restrict__ bc2,
                                                         const float* __restrict__ Wc3,
                                                         const float* __restrict__ bc3,
                                                         float* __restrict__ outp, int B) {
    __shared__ float z[256];
    __shared__ float a1[128];
    __shared__ float a2[64];
    int r = blockIdx.x, t = threadIdx.x;
    float ct = (float)max(cnt[r], 1);
    float cp = (float)max(cnt[B + r], 1);
    z[t]       = pooled[(size_t)r * 256 + t] / ct;
    z[128 + t] = pooled[(size_t)r * 256 + 128 + t] / cp;
    __syncthreads();
    float acc = bc1[t];
    for (int k = 0; k < 256; ++k) acc = fmaf(z[k], Wc1[k * 128 + t], acc);
    a1[t] = fmaxf(acc, 0.f);
    __syncthreads();
    if (t < 64) {
        float a = bc2[t];
        for (int k = 0; k < 128; ++k) a = fmaf(a1[k], Wc2[k * 64 + t], a);
        a2[t] = fmaxf(a, 0.f);
    }
    __syncthreads();
    if (t < 64) {
        float p = a2[t] * Wc3[t];
#pragma unroll
        for (int k = 1; k < 64; k <<= 1) p += __shfl_xor(p, k);
        if (t == 0) outp[r] = 1.f / (1.f + __expf(-(p + bc3[0])));
    }
}

// ---------------------------------------------------------------------------
// Host orchestration — single combined graph, fp16 h2, split softmax/gather.
// ---------------------------------------------------------------------------
extern "C" void kernel_launch(void* const* d_in, const int* in_sizes, int n_in,
                              void* d_out, int out_size, void* d_ws, size_t ws_size,
                              hipStream_t stream) {
    const float* tcr_x     = (const float*)d_in[0];
    const int*   tcr_ei    = (const int*)d_in[1];
    const int*   tcr_batch = (const int*)d_in[2];
    const float* pep_x     = (const float*)d_in[3];
    const int*   pep_ei    = (const int*)d_in[4];
    const int*   pep_batch = (const int*)d_in[5];
    const float* W_in      = (const float*)d_in[6];
    const float* b_in      = (const float*)d_in[7];
    const float* Wg        = (const float*)d_in[8];
    const float* bg        = (const float*)d_in[9];
    const float* att_src   = (const float*)d_in[10];
    const float* att_dst   = (const float*)d_in[11];
    const float* ln_gamma  = (const float*)d_in[12];
    const float* ln_beta   = (const float*)d_in[13];
    const float* Wc1       = (const float*)d_in[14];
    const float* bc1       = (const float*)d_in[15];
    const float* Wc2       = (const float*)d_in[16];
    const float* bc2       = (const float*)d_in[17];
    const float* Wc3       = (const float*)d_in[18];
    const float* bc3       = (const float*)d_in[19];

    const int Nt = in_sizes[0] / DIN;
    const int Et = in_sizes[1] / 2;
    const int Np = in_sizes[3] / DIN;
    const int Ep = in_sizes[4] / 2;
    const int B  = out_size;
    const int N  = Nt + Np;
    const int Etot = Et + Ep + N;

    char* w = (char*)d_ws;
    size_t o = 0;
    auto alloc = [&](size_t bytes) -> char* {
        size_t r = (o + 255) & ~(size_t)255;
        o = r + bytes;
        return w + r;
    };
    float*  pooled = (float*)alloc((size_t)B * 256 * 4);
    int*    cnt    = (int*)alloc((size_t)B * 2 * 4);
    float*  h_a    = (float*)alloc((size_t)N * 128 * 4);   // residual stream (f32)
    __half* h2h    = (__half*)alloc((size_t)N * 128 * 2);  // projected feats (fp16)
    float*  ssrc   = (float*)alloc((size_t)N * 4 * 4);
    float*  sdst   = (float*)alloc((size_t)N * 4 * 4);
    float*  zbuf   = (float*)alloc((size_t)N * 4 * 4);
    float*  alphaB = (float*)alloc((size_t)Etot * 4 * 4);
    int* rowptr    = (int*)alloc((size_t)(N + 1) * 4);
    int* cursor    = (int*)alloc((size_t)N * 4);
    int* deg       = (int*)alloc((size_t)N * 4);
    int* part      = (int*)alloc(256 * 4);
    int* col       = (int*)alloc((size_t)Etot * 4);
    (void)ws_size; (void)n_in;

    hipMemsetAsync(pooled, 0, (size_t)B * 256 * 4, stream);
    hipMemsetAsync(cnt, 0, (size_t)B * 2 * 4, stream);
    hipMemsetAsync(deg, 0, (size_t)N * 4, stream);

    // CSR build (combined, built once, reused by all 3 layers)
    hist_kernel<<<(Etot + 255) / 256, 256, 0, stream>>>(tcr_ei, pep_ei, deg, Et, Ep, Nt, N);
    int nblk = (N + 1023) / 1024;
    scan_reduce<<<nblk, 256, 0, stream>>>(deg, part, N);
    scan_partials<<<1, 256, 0, stream>>>(part, rowptr, nblk, N);
    scan_final<<<nblk, 256, 0, stream>>>(deg, part, rowptr, cursor, N);
    fill_kernel<<<(Etot + 255) / 256, 256, 0, stream>>>(tcr_ei, pep_ei, cursor, col, Et, Ep, Nt, N);

    // Input projection + relu -> combined residual stream
    gemm128_f32<<<Nt / 64, 256, 0, stream>>>(tcr_x, W_in, b_in, h_a, Nt, DIN);
    gemm128_f32<<<Np / 64, 256, 0, stream>>>(pep_x, W_in, b_in, h_a + (size_t)Nt * 128, Np, DIN);

    for (int i = 0; i < NLAYERS; ++i) {
        gemm128_f16<<<N / 64, 256, 0, stream>>>(h_a, Wg + (size_t)i * HIDDIM * HIDDIM,
                                                h2h, N, HIDDIM);
        scores_kernel<<<(N + 3) / 4, 256, 0, stream>>>((const __half2*)h2h,
                                                       att_src + i * NHEAD * CDIM,
                                                       att_dst + i * NHEAD * CDIM,
                                                       ssrc, sdst, N);
        alpha_kernel<<<(N + 15) / 16, 256, 0, stream>>>((const float4*)ssrc, (const float4*)sdst,
                                                        rowptr, col, (float4*)alphaB,
                                                        (float4*)zbuf, N);
        gather_kernel<<<(N + 3) / 4, 256, 0, stream>>>((const __half2*)h2h, alphaB, zbuf,
                                                       rowptr, col, bg + i * HIDDIM,
                                                       ln_gamma + i * HIDDIM,
                                                       ln_beta + i * HIDDIM, h_a, N);
    }
    pool_kernel<<<(N + 3) / 4, 256, 0, stream>>>(h_a, tcr_batch, pep_batch, pooled, cnt, Nt, N, B);

    classifier_kernel<<<B, 128, 0, stream>>>(pooled, cnt, Wc1, bc1, Wc2, bc2,
                                             Wc3, bc3, (float*)d_out, B);
}

// Round 4
// 1463.126 us; speedup vs baseline: 1.7939x; 1.4454x over previous
//
#include <hip/hip_runtime.h>
#include <hip/hip_fp16.h>
#include <math.h>

// Problem constants: H=4 heads, C=32, HID=128, 3 layers, B=2048, D=480
#define NHEAD   4
#define CDIM    32
#define HIDDIM  128
#define NLAYERS 3
#define DIN     480
#define LN_EPS  1e-5f

typedef _Float16 f16x8 __attribute__((ext_vector_type(8)));
typedef float    f32x4 __attribute__((ext_vector_type(4)));

// ---------------------------------------------------------------------------
// Combined-graph CSR build. Node ids: tcr [0,Nt), pep [Nt,Nt+Np).
// ---------------------------------------------------------------------------
__global__ void hist_kernel(const int* __restrict__ tei, const int* __restrict__ pei,
                            int* __restrict__ deg, int Et, int Ep, int Nt, int N) {
    int i = blockIdx.x * 256 + threadIdx.x;
    int tot = Et + Ep + N;
    if (i >= tot) return;
    int d;
    if (i < Et)            d = tei[Et + i];
    else if (i < Et + Ep)  d = pei[Ep + (i - Et)] + Nt;
    else                   d = i - Et - Ep;
    atomicAdd(&deg[d], 1);
}

__global__ void fill_kernel(const int* __restrict__ tei, const int* __restrict__ pei,
                            int* __restrict__ cursor, int* __restrict__ col,
                            int Et, int Ep, int Nt, int N) {
    int i = blockIdx.x * 256 + threadIdx.x;
    int tot = Et + Ep + N;
    if (i >= tot) return;
    int s, d;
    if (i < Et)           { s = tei[i]; d = tei[Et + i]; }
    else if (i < Et + Ep) { int j = i - Et; s = pei[j] + Nt; d = pei[Ep + j] + Nt; }
    else                  { s = d = i - Et - Ep; }
    int pos = atomicAdd(&cursor[d], 1);
    col[pos] = s;
}

// ---------------------------------------------------------------------------
// Hierarchical exclusive scan: 1024 elems/block, int4 coalesced.
// ---------------------------------------------------------------------------
__global__ __launch_bounds__(256) void scan_reduce(const int* __restrict__ deg,
                                                   int* __restrict__ part, int N) {
    __shared__ int sm[256];
    int t = threadIdx.x;
    int base = blockIdx.x * 1024 + t * 4;
    int4 v = make_int4(0, 0, 0, 0);
    if (base + 3 < N) v = *(const int4*)(deg + base);
    else if (base < N) {
        v.x = deg[base];
        if (base + 1 < N) v.y = deg[base + 1];
        if (base + 2 < N) v.z = deg[base + 2];
    }
    sm[t] = v.x + v.y + v.z + v.w;
    __syncthreads();
    for (int off = 128; off >= 1; off >>= 1) {
        if (t < off) sm[t] += sm[t + off];
        __syncthreads();
    }
    if (t == 0) part[blockIdx.x] = sm[0];
}

__global__ __launch_bounds__(256) void scan_partials(int* __restrict__ part,
                                                     int* __restrict__ rowptr,
                                                     int npart, int N) {
    __shared__ int sm[256];
    int t = threadIdx.x;
    sm[t] = (t < npart) ? part[t] : 0;
    __syncthreads();
    for (int off = 1; off < 256; off <<= 1) {
        int u = (t >= off) ? sm[t - off] : 0;
        __syncthreads();
        sm[t] += u;
        __syncthreads();
    }
    if (t < npart) part[t] = (t == 0) ? 0 : sm[t - 1];
    if (t == 0) rowptr[N] = sm[255];
}

__global__ __launch_bounds__(256) void scan_final(const int* __restrict__ deg,
                                                  const int* __restrict__ part,
                                                  int* __restrict__ rowptr,
                                                  int* __restrict__ cursor, int N) {
    __shared__ int sm[256];
    int t = threadIdx.x;
    int base = blockIdx.x * 1024 + t * 4;
    int4 v = make_int4(0, 0, 0, 0);
    if (base + 3 < N) v = *(const int4*)(deg + base);
    else if (base < N) {
        v.x = deg[base];
        if (base + 1 < N) v.y = deg[base + 1];
        if (base + 2 < N) v.z = deg[base + 2];
    }
    sm[t] = v.x + v.y + v.z + v.w;
    __syncthreads();
    for (int off = 1; off < 256; off <<= 1) {
        int u = (t >= off) ? sm[t - off] : 0;
        __syncthreads();
        sm[t] += u;
        __syncthreads();
    }
    int run = ((t == 0) ? 0 : sm[t - 1]) + part[blockIdx.x];
    if (base < N)     { rowptr[base]     = run; cursor[base]     = run; run += v.x; }
    if (base + 1 < N) { rowptr[base + 1] = run; cursor[base + 1] = run; run += v.y; }
    if (base + 2 < N) { rowptr[base + 2] = run; cursor[base + 2] = run; run += v.z; }
    if (base + 3 < N) { rowptr[base + 3] = run; cursor[base + 3] = run; }
}

// ---------------------------------------------------------------------------
// Weight prep: W [K][128] f32 -> Wt [128][K] f16 (transposed, cast).
// ---------------------------------------------------------------------------
__global__ void transpose_w(const float* __restrict__ W, _Float16* __restrict__ Wt,
                            int K) {
    int idx = blockIdx.x * 256 + threadIdx.x;
    if (idx >= K * 128) return;
    int n = idx / K, k = idx - n * K;
    Wt[idx] = (_Float16)W[(size_t)k * 128 + n];
}

// ---------------------------------------------------------------------------
// MFMA fp16 GEMM: C[n,j] = act(A[n,:] @ W[:,j] (+bias)), 128 output cols.
// Block 256 (4 waves); tile 64 rows x 128 cols; K-step 32.
// Wt is pre-transposed [128][K] f16. A is f32, cast to f16 during staging.
// Fragment layouts (gfx950 16x16x32): A/B lane: [m|n=lane&15][k=quad*8+j];
// C/D lane: col=lane&15, row=quad*4+reg.   OUT_F16: f16 out, no bias/act.
// ---------------------------------------------------------------------------
#define ASTRIDE 40   // halves; 80 B row stride: 16B-aligned, 2-way banks (free)

template<int OUT_F16>
__global__ __launch_bounds__(256) void mfma_gemm(const float* __restrict__ A,
                                                 const _Float16* __restrict__ Wt,
                                                 const float* __restrict__ bias,
                                                 void* __restrict__ Cout,
                                                 int K) {
    __shared__ _Float16 As[64 * ASTRIDE];
    __shared__ _Float16 Ws[128 * ASTRIDE];
    const int tid  = threadIdx.x;
    const int bn   = blockIdx.x * 64;
    const int wave = tid >> 6, lane = tid & 63;
    const int lm   = lane & 15, q = lane >> 4;

    f32x4 acc[8];
#pragma unroll
    for (int i = 0; i < 8; ++i) acc[i] = (f32x4){0.f, 0.f, 0.f, 0.f};

    for (int kt = 0; kt < K; kt += 32) {
        // Stage A tile: 64 rows x 32 cols, f32 -> f16 (coalesced float4 loads)
#pragma unroll
        for (int p = 0; p < 2; ++p) {
            int f  = p * 256 + tid;          // float4 index in [0,512)
            int r  = f >> 3;
            int c4 = (f & 7) * 4;
            float4 v = *(const float4*)(A + (size_t)(bn + r) * K + kt + c4);
            _Float16* d = &As[r * ASTRIDE + c4];
            d[0] = (_Float16)v.x; d[1] = (_Float16)v.y;
            d[2] = (_Float16)v.z; d[3] = (_Float16)v.w;
        }
        // Stage Wt tile: 128 rows(n) x 32 k halves (straight copy, coalesced)
#pragma unroll
        for (int p = 0; p < 2; ++p) {
            int f   = p * 256 + tid;         // 8-half segment index in [0,512)
            int n   = f >> 2;
            int seg = (f & 3) * 8;
            *(float4*)(&Ws[n * ASTRIDE + seg]) =
                *(const float4*)(Wt + (size_t)n * K + kt + seg);
        }
        __syncthreads();
        f16x8 af = *(const f16x8*)(&As[(wave * 16 + lm) * ASTRIDE + q * 8]);
#pragma unroll
        for (int nt = 0; nt < 8; ++nt) {
            f16x8 bf = *(const f16x8*)(&Ws[(nt * 16 + lm) * ASTRIDE + q * 8]);
            acc[nt] = __builtin_amdgcn_mfma_f32_16x16x32_f16(af, bf, acc[nt], 0, 0, 0);
        }
        __syncthreads();
    }

    const int row0 = bn + wave * 16 + q * 4;
    if (OUT_F16) {
        _Float16* C = (_Float16*)Cout;
#pragma unroll
        for (int nt = 0; nt < 8; ++nt) {
            int c = nt * 16 + lm;
#pragma unroll
            for (int i = 0; i < 4; ++i)
                C[(size_t)(row0 + i) * 128 + c] = (_Float16)acc[nt][i];
        }
    } else {
        float* C = (float*)Cout;
#pragma unroll
        for (int nt = 0; nt < 8; ++nt) {
            int c = nt * 16 + lm;
            float bv = bias[c];
#pragma unroll
            for (int i = 0; i < 4; ++i)
                C[(size_t)(row0 + i) * 128 + c] = fmaxf(acc[nt][i] + bv, 0.f);
        }
    }
}

// ---------------------------------------------------------------------------
// Attention scores from fp16 h2. One wave per node; lane l -> ch 2l,2l+1,
// head = l>>4. 16-lane group reduction -> ssrc[n*4+h], sdst[n*4+h].
// ---------------------------------------------------------------------------
__global__ __launch_bounds__(256) void scores_kernel(const __half2* __restrict__ h2v,
                                                     const float* __restrict__ a_src,
                                                     const float* __restrict__ a_dst,
                                                     float* __restrict__ ssrc,
                                                     float* __restrict__ sdst, int N) {
    int wave = threadIdx.x >> 6, lane = threadIdx.x & 63;
    int n = blockIdx.x * 4 + wave;
    if (n >= N) return;
    int c = lane * 2, h = lane >> 4, t = lane & 15;
    float2 v = __half22float2(h2v[(size_t)n * 64 + lane]);
    float2 as = *(const float2*)(a_src + c);
    float2 ad = *(const float2*)(a_dst + c);
    float ps = v.x * as.x + v.y * as.y;
    float pd = v.x * ad.x + v.y * ad.y;
#pragma unroll
    for (int k = 1; k < 16; k <<= 1) {
        ps += __shfl_xor(ps, k, 16);
        pd += __shfl_xor(pd, k, 16);
    }
    if (t == 0) {
        ssrc[n * 4 + h] = ps;
        sdst[n * 4 + h] = pd;
    }
}

// ---------------------------------------------------------------------------
// Phase 1: per-edge softmax weights. 16 lanes per node, 4 nodes per wave.
// Pass A: max (recompute e). Pass B: p = exp(e-m), single write; z reduce.
// ---------------------------------------------------------------------------
__global__ __launch_bounds__(256) void alpha_kernel(const float4* __restrict__ ssrc4,
                                                    const float4* __restrict__ sdst4,
                                                    const int* __restrict__ rowptr,
                                                    const int* __restrict__ col,
                                                    float4* __restrict__ alpha4,
                                                    float4* __restrict__ zbuf4, int N) {
    int wave = threadIdx.x >> 6, lane = threadIdx.x & 63;
    int g = lane >> 4, t = lane & 15;
    int n = blockIdx.x * 16 + wave * 4 + g;
    bool valid = n < N;
    int nn = valid ? n : 0;
    float4 sd = sdst4[nn];
    int beg = valid ? rowptr[nn] : 0;
    int end = valid ? rowptr[nn + 1] : 0;

    float m0 = -1e30f, m1 = -1e30f, m2 = -1e30f, m3 = -1e30f;
    for (int j = beg + t; j < end; j += 16) {
        int s = col[j];
        float4 ss = ssrc4[s];
        float e0 = ss.x + sd.x; e0 = e0 > 0.f ? e0 : 0.2f * e0;
        float e1 = ss.y + sd.y; e1 = e1 > 0.f ? e1 : 0.2f * e1;
        float e2 = ss.z + sd.z; e2 = e2 > 0.f ? e2 : 0.2f * e2;
        float e3 = ss.w + sd.w; e3 = e3 > 0.f ? e3 : 0.2f * e3;
        m0 = fmaxf(m0, e0); m1 = fmaxf(m1, e1);
        m2 = fmaxf(m2, e2); m3 = fmaxf(m3, e3);
    }
#pragma unroll
    for (int k = 1; k < 16; k <<= 1) {
        m0 = fmaxf(m0, __shfl_xor(m0, k, 16));
        m1 = fmaxf(m1, __shfl_xor(m1, k, 16));
        m2 = fmaxf(m2, __shfl_xor(m2, k, 16));
        m3 = fmaxf(m3, __shfl_xor(m3, k, 16));
    }
    float z0 = 0.f, z1 = 0.f, z2 = 0.f, z3 = 0.f;
    for (int j = beg + t; j < end; j += 16) {
        int s = col[j];
        float4 ss = ssrc4[s];
        float e0 = ss.x + sd.x; e0 = e0 > 0.f ? e0 : 0.2f * e0;
        float e1 = ss.y + sd.y; e1 = e1 > 0.f ? e1 : 0.2f * e1;
        float e2 = ss.z + sd.z; e2 = e2 > 0.f ? e2 : 0.2f * e2;
        float e3 = ss.w + sd.w; e3 = e3 > 0.f ? e3 : 0.2f * e3;
        float p0 = __expf(e0 - m0);
        float p1 = __expf(e1 - m1);
        float p2 = __expf(e2 - m2);
        float p3 = __expf(e3 - m3);
        alpha4[j] = make_float4(p0, p1, p2, p3);
        z0 += p0; z1 += p1; z2 += p2; z3 += p3;
    }
#pragma unroll
    for (int k = 1; k < 16; k <<= 1) {
        z0 += __shfl_xor(z0, k, 16);
        z1 += __shfl_xor(z1, k, 16);
        z2 += __shfl_xor(z2, k, 16);
        z3 += __shfl_xor(z3, k, 16);
    }
    if (valid && t == 0) zbuf4[nn] = make_float4(z0, z1, z2, z3);
}

// ---------------------------------------------------------------------------
// Phase 2: gather a += p*v (fp16 values), 4-edge unrolled for MLP, then
// /z + bias + LayerNorm + ReLU + residual in place. One wave per node.
// ---------------------------------------------------------------------------
__global__ __launch_bounds__(256) void gather_kernel(const __half2* __restrict__ h2v,
                                                     const float* __restrict__ alphaF,
                                                     const float* __restrict__ zF,
                                                     const int* __restrict__ rowptr,
                                                     const int* __restrict__ col,
                                                     const float* __restrict__ bg,
                                                     const float* __restrict__ gamma,
                                                     const float* __restrict__ beta,
                                                     float* __restrict__ hio, int N) {
    int wave = threadIdx.x >> 6, lane = threadIdx.x & 63;
    int n = blockIdx.x * 4 + wave;
    if (n >= N) return;
    int c = lane * 2, h = lane >> 4;
    int beg = rowptr[n], end = rowptr[n + 1];
    float a0 = 0.f, a1 = 0.f;
    int j = beg;
    for (; j + 3 < end; j += 4) {
        int s0 = col[j], s1 = col[j + 1], s2 = col[j + 2], s3 = col[j + 3];
        float p0 = alphaF[(size_t)j * 4 + h];
        float p1 = alphaF[(size_t)(j + 1) * 4 + h];
        float p2 = alphaF[(size_t)(j + 2) * 4 + h];
        float p3 = alphaF[(size_t)(j + 3) * 4 + h];
        float2 v0 = __half22float2(h2v[(size_t)s0 * 64 + lane]);
        float2 v1 = __half22float2(h2v[(size_t)s1 * 64 + lane]);
        float2 v2 = __half22float2(h2v[(size_t)s2 * 64 + lane]);
        float2 v3 = __half22float2(h2v[(size_t)s3 * 64 + lane]);
        a0 = fmaf(p0, v0.x, a0); a1 = fmaf(p0, v0.y, a1);
        a0 = fmaf(p1, v1.x, a0); a1 = fmaf(p1, v1.y, a1);
        a0 = fmaf(p2, v2.x, a0); a1 = fmaf(p2, v2.y, a1);
        a0 = fmaf(p3, v3.x, a0); a1 = fmaf(p3, v3.y, a1);
    }
    for (; j < end; ++j) {
        int s = col[j];
        float p = alphaF[(size_t)j * 4 + h];
        float2 v = __half22float2(h2v[(size_t)s * 64 + lane]);
        a0 = fmaf(p, v.x, a0);
        a1 = fmaf(p, v.y, a1);
    }
    float inv = 1.f / zF[n * 4 + h];
    float2 bgv = *(const float2*)(bg + c);
    float o0 = a0 * inv + bgv.x;
    float o1 = a1 * inv + bgv.y;
    float s = o0 + o1;
#pragma unroll
    for (int k = 1; k < 64; k <<= 1) s += __shfl_xor(s, k);
    float mu = s * (1.f / 128.f);
    float q = (o0 - mu) * (o0 - mu) + (o1 - mu) * (o1 - mu);
#pragma unroll
    for (int k = 1; k < 64; k <<= 1) q += __shfl_xor(q, k);
    float rs = rsqrtf(q * (1.f / 128.f) + LN_EPS);
    float2 gm = *(const float2*)(gamma + c);
    float2 bt = *(const float2*)(beta + c);
    float y0 = (o0 - mu) * rs * gm.x + bt.x;
    float y1 = (o1 - mu) * rs * gm.y + bt.y;
    float2 r = *(const float2*)(hio + (size_t)n * 128 + c);
    y0 = fmaxf(y0, 0.f) + r.x;
    y1 = fmaxf(y1, 0.f) + r.y;
    *(float2*)(hio + (size_t)n * 128 + c) = make_float2(y0, y1);
}

// ---------------------------------------------------------------------------
// Global mean pool. tcr -> pooled[b][0:128], cnt[b]; pep -> [128:256], cnt[B+b].
// ---------------------------------------------------------------------------
__global__ __launch_bounds__(256) void pool_kernel(const float* __restrict__ h,
                                                   const int* __restrict__ tb,
                                                   const int* __restrict__ pb,
                                                   float* __restrict__ pooled,
                                                   int* __restrict__ cnt,
                                                   int Nt, int N, int B) {
    int wave = threadIdx.x >> 6, lane = threadIdx.x & 63;
    int n = blockIdx.x * 4 + wave;
    if (n >= N) return;
    int b, off, ci;
    if (n < Nt) { b = tb[n];      off = 0;   ci = b; }
    else        { b = pb[n - Nt]; off = 128; ci = B + b; }
    float v0 = h[(size_t)n * 128 + lane];
    float v1 = h[(size_t)n * 128 + 64 + lane];
    atomicAdd(&pooled[(size_t)b * 256 + off + lane], v0);
    atomicAdd(&pooled[(size_t)b * 256 + off + 64 + lane], v1);
    if (lane == 0) atomicAdd(&cnt[ci], 1);
}

// ---------------------------------------------------------------------------
// Classifier MLP: [B,256] -> relu 128 -> relu 64 -> sigmoid 1. Block per row.
// ---------------------------------------------------------------------------
__global__ __launch_bounds__(128) void classifier_kernel(const float* __restrict__ pooled,
                                                         const int* __restrict__ cnt,
                                                         const float* __restrict__ Wc1,
                                                         const float* __restrict__ bc1,
                                                         const float* __restrict__ Wc2,
                                                         const float* __restrict__ bc2,
                                                         const float* __restrict__ Wc3,
                                                         const float* __restrict__ bc3,
                                                         float* __restrict__ outp, int B) {
    __shared__ float z[256];
    __shared__ float a1[128];
    __shared__ float a2[64];
    int r = blockIdx.x, t = threadIdx.x;
    float ct = (float)max(cnt[r], 1);
    float cp = (float)max(cnt[B + r], 1);
    z[t]       = pooled[(size_t)r * 256 + t] / ct;
    z[128 + t] = pooled[(size_t)r * 256 + 128 + t] / cp;
    __syncthreads();
    float acc = bc1[t];
    for (int k = 0; k < 256; ++k) acc = fmaf(z[k], Wc1[k * 128 + t], acc);
    a1[t] = fmaxf(acc, 0.f);
    __syncthreads();
    if (t < 64) {
        float a = bc2[t];
        for (int k = 0; k < 128; ++k) a = fmaf(a1[k], Wc2[k * 64 + t], a);
        a2[t] = fmaxf(a, 0.f);
    }
    __syncthreads();
    if (t < 64) {
        float p = a2[t] * Wc3[t];
#pragma unroll
        for (int k = 1; k < 64; k <<= 1) p += __shfl_xor(p, k);
        if (t == 0) outp[r] = 1.f / (1.f + __expf(-(p + bc3[0])));
    }
}

// ---------------------------------------------------------------------------
// Host orchestration — combined graph, fp16 MFMA GEMMs, split softmax/gather.
// ---------------------------------------------------------------------------
extern "C" void kernel_launch(void* const* d_in, const int* in_sizes, int n_in,
                              void* d_out, int out_size, void* d_ws, size_t ws_size,
                              hipStream_t stream) {
    const float* tcr_x     = (const float*)d_in[0];
    const int*   tcr_ei    = (const int*)d_in[1];
    const int*   tcr_batch = (const int*)d_in[2];
    const float* pep_x     = (const float*)d_in[3];
    const int*   pep_ei    = (const int*)d_in[4];
    const int*   pep_batch = (const int*)d_in[5];
    const float* W_in      = (const float*)d_in[6];
    const float* b_in      = (const float*)d_in[7];
    const float* Wg        = (const float*)d_in[8];
    const float* bg        = (const float*)d_in[9];
    const float* att_src   = (const float*)d_in[10];
    const float* att_dst   = (const float*)d_in[11];
    const float* ln_gamma  = (const float*)d_in[12];
    const float* ln_beta   = (const float*)d_in[13];
    const float* Wc1       = (const float*)d_in[14];
    const float* bc1       = (const float*)d_in[15];
    const float* Wc2       = (const float*)d_in[16];
    const float* bc2       = (const float*)d_in[17];
    const float* Wc3       = (const float*)d_in[18];
    const float* bc3       = (const float*)d_in[19];

    const int Nt = in_sizes[0] / DIN;
    const int Et = in_sizes[1] / 2;
    const int Np = in_sizes[3] / DIN;
    const int Ep = in_sizes[4] / 2;
    const int B  = out_size;
    const int N  = Nt + Np;
    const int Etot = Et + Ep + N;

    char* w = (char*)d_ws;
    size_t o = 0;
    auto alloc = [&](size_t bytes) -> char* {
        size_t r = (o + 255) & ~(size_t)255;
        o = r + bytes;
        return w + r;
    };
    float*    pooled = (float*)alloc((size_t)B * 256 * 4);
    int*      cnt    = (int*)alloc((size_t)B * 2 * 4);
    float*    h_a    = (float*)alloc((size_t)N * 128 * 4);   // residual stream (f32)
    _Float16* h2h    = (_Float16*)alloc((size_t)N * 128 * 2); // projected feats (f16)
    _Float16* WtIn   = (_Float16*)alloc((size_t)128 * DIN * 2);
    _Float16* WtG    = (_Float16*)alloc((size_t)NLAYERS * 128 * 128 * 2);
    float*    ssrc   = (float*)alloc((size_t)N * 4 * 4);
    float*    sdst   = (float*)alloc((size_t)N * 4 * 4);
    float*    zbuf   = (float*)alloc((size_t)N * 4 * 4);
    float*    alphaB = (float*)alloc((size_t)Etot * 4 * 4);
    int* rowptr      = (int*)alloc((size_t)(N + 1) * 4);
    int* cursor      = (int*)alloc((size_t)N * 4);
    int* deg         = (int*)alloc((size_t)N * 4);
    int* part        = (int*)alloc(256 * 4);
    int* col         = (int*)alloc((size_t)Etot * 4);
    (void)ws_size; (void)n_in;

    hipMemsetAsync(pooled, 0, (size_t)B * 256 * 4, stream);
    hipMemsetAsync(cnt, 0, (size_t)B * 2 * 4, stream);
    hipMemsetAsync(deg, 0, (size_t)N * 4, stream);

    // Weight prep (transpose + f16 cast)
    transpose_w<<<(128 * DIN + 255) / 256, 256, 0, stream>>>(W_in, WtIn, DIN);
    for (int i = 0; i < NLAYERS; ++i)
        transpose_w<<<(128 * 128 + 255) / 256, 256, 0, stream>>>(
            Wg + (size_t)i * HIDDIM * HIDDIM, WtG + (size_t)i * 128 * 128, 128);

    // CSR build (combined, built once, reused by all 3 layers)
    hist_kernel<<<(Etot + 255) / 256, 256, 0, stream>>>(tcr_ei, pep_ei, deg, Et, Ep, Nt, N);
    int nblk = (N + 1023) / 1024;
    scan_reduce<<<nblk, 256, 0, stream>>>(deg, part, N);
    scan_partials<<<1, 256, 0, stream>>>(part, rowptr, nblk, N);
    scan_final<<<nblk, 256, 0, stream>>>(deg, part, rowptr, cursor, N);
    fill_kernel<<<(Etot + 255) / 256, 256, 0, stream>>>(tcr_ei, pep_ei, cursor, col, Et, Ep, Nt, N);

    // Input projection + relu -> combined residual stream (MFMA f16)
    mfma_gemm<0><<<Nt / 64, 256, 0, stream>>>(tcr_x, WtIn, b_in, h_a, DIN);
    mfma_gemm<0><<<Np / 64, 256, 0, stream>>>(pep_x, WtIn, b_in, h_a + (size_t)Nt * 128, DIN);

    for (int i = 0; i < NLAYERS; ++i) {
        mfma_gemm<1><<<N / 64, 256, 0, stream>>>(h_a, WtG + (size_t)i * 128 * 128,
                                                 nullptr, h2h, 128);
        scores_kernel<<<(N + 3) / 4, 256, 0, stream>>>((const __half2*)h2h,
                                                       att_src + i * NHEAD * CDIM,
                                                       att_dst + i * NHEAD * CDIM,
                                                       ssrc, sdst, N);
        alpha_kernel<<<(N + 15) / 16, 256, 0, stream>>>((const float4*)ssrc, (const float4*)sdst,
                                                        rowptr, col, (float4*)alphaB,
                                                        (float4*)zbuf, N);
        gather_kernel<<<(N + 3) / 4, 256, 0, stream>>>((const __half2*)h2h, alphaB, zbuf,
                                                       rowptr, col, bg + i * HIDDIM,
                                                       ln_gamma + i * HIDDIM,
                                                       ln_beta + i * HIDDIM, h_a, N);
    }
    pool_kernel<<<(N + 3) / 4, 256, 0, stream>>>(h_a, tcr_batch, pep_batch, pooled, cnt, Nt, N, B);

    classifier_kernel<<<B, 128, 0, stream>>>(pooled, cnt, Wc1, bc1, Wc2, bc2,
                                             Wc3, bc3, (float*)d_out, B);
}